// Round 1
// baseline (194.720 us; speedup 1.0000x reference)
//
#include <hip/hip_runtime.h>

#define B_    64
#define T_    512
#define DIN   512
#define DHID  1024
#define DOUT  512
#define NDAYS 24

typedef unsigned short u16;
typedef __bf16 bf16x8 __attribute__((ext_vector_type(8)));
typedef u16    u16x8  __attribute__((ext_vector_type(8)));
typedef float  f32x4  __attribute__((ext_vector_type(4)));

static __device__ __forceinline__ u16 f2bf(float f) {
    union { float f; unsigned u; } v; v.f = f;
    unsigned r = v.u + 0x7FFFu + ((v.u >> 16) & 1u);
    return (u16)(r >> 16);
}

static __device__ __forceinline__ void gload_lds16(const void* g, void* l) {
    __builtin_amdgcn_global_load_lds(
        (const __attribute__((address_space(1))) void*)g,
        (__attribute__((address_space(3))) void*)l, 16, 0, 0);
}

// W[d][R][C] fp32  ->  WT[d][C][R] bf16   (B^T layout for MFMA B operand)
__global__ __launch_bounds__(256)
void transpose_w(const float* __restrict__ W, u16* __restrict__ WT, int R, int C) {
    __shared__ float t[32][33];
    const int d  = blockIdx.z;
    const int r0 = blockIdx.y * 32, c0 = blockIdx.x * 32;
    const int tx = threadIdx.x, ty = threadIdx.y;   // 32 x 8
    const float* Wd = W + (size_t)d * R * C;
    u16* WTd = WT + (size_t)d * R * C;
#pragma unroll
    for (int i = 0; i < 4; ++i)
        t[ty + i * 8][tx] = Wd[(size_t)(r0 + ty + i * 8) * C + c0 + tx];
    __syncthreads();
#pragma unroll
    for (int i = 0; i < 4; ++i)
        WTd[(size_t)(c0 + ty + i * 8) * R + r0 + tx] = f2bf(t[tx][ty + i * 8]);
}

// C[bz] = act(A[bz] @ BT[day]^T + bias[day]); 128x128 tile, 4 waves 2x2, BK=64.
// LDS layout [row][64] bf16 with 16B-chunk XOR swizzle: slot s of row r holds
// global chunk s^(r&7); readers use slot = chunk^(r&7).
template<int MT, int NT, int KT, bool A_F32, bool RELU, bool OUT_BF16>
__global__ __launch_bounds__(256)
void gemm_day(const void* __restrict__ Aall,
              const u16*  __restrict__ BT,     // [NDAYS][NT][KT] bf16
              const float* __restrict__ bias,  // [NDAYS][NT]
              const int*  __restrict__ didx,
              void* __restrict__ Call)
{
    const int bz  = blockIdx.z;
    const int day = didx[bz];
    const int m0  = blockIdx.x * 128;
    const int n0  = blockIdx.y * 128;
    const int tid = threadIdx.x;
    const int wv  = tid >> 6, ln = tid & 63;
    const int wm  = wv >> 1, wn = wv & 1;

    __shared__ __align__(16) u16 sA[128 * 64];
    __shared__ __align__(16) u16 sB[128 * 64];

    const u16* Bt = BT + (size_t)day * NT * KT + (size_t)n0 * KT;
    const float* Af = (const float*)Aall + (size_t)bz * MT * KT + (size_t)m0 * KT;
    const u16*  Ab  = (const u16*)Aall  + (size_t)bz * MT * KT + (size_t)m0 * KT;

    f32x4 acc[4][4];
#pragma unroll
    for (int i = 0; i < 4; ++i)
#pragma unroll
        for (int j = 0; j < 4; ++j)
            acc[i][j] = (f32x4){0.f, 0.f, 0.f, 0.f};

    for (int kt = 0; kt < KT; kt += 64) {
        // ---- stage B (bf16) via global_load_lds, pre-swizzled source ----
#pragma unroll
        for (int i = 0; i < 4; ++i) {
            const int blk = i * 4 + wv;
            const int r   = blk * 8 + (ln >> 3);
            const int cd  = (ln & 7) ^ (r & 7);
            gload_lds16(Bt + (size_t)r * KT + kt + cd * 8, (char*)sB + blk * 1024);
        }
        // ---- stage A ----
        if (A_F32) {
            // fp32 -> bf16 reg-staged, direct swizzled ds_write
#pragma unroll
            for (int i = 0; i < 4; ++i) {
                const int chunk = i * 256 + tid;     // 1024 chunks of 8 elems
                const int r  = chunk >> 3;
                const int s  = chunk & 7;
                const int cd = s ^ (r & 7);
                const float* src = Af + (size_t)r * KT + kt + cd * 8;
                float4 x0 = *(const float4*)(src);
                float4 x1 = *(const float4*)(src + 4);
                u16x8 pk;
                pk[0] = f2bf(x0.x); pk[1] = f2bf(x0.y);
                pk[2] = f2bf(x0.z); pk[3] = f2bf(x0.w);
                pk[4] = f2bf(x1.x); pk[5] = f2bf(x1.y);
                pk[6] = f2bf(x1.z); pk[7] = f2bf(x1.w);
                *(u16x8*)&sA[r * 64 + s * 8] = pk;
            }
        } else {
#pragma unroll
            for (int i = 0; i < 4; ++i) {
                const int blk = i * 4 + wv;
                const int r   = blk * 8 + (ln >> 3);
                const int cd  = (ln & 7) ^ (r & 7);
                gload_lds16(Ab + (size_t)r * KT + kt + cd * 8, (char*)sA + blk * 1024);
            }
        }
        __syncthreads();

        // ---- compute: 2 k-steps x 4x4 fragments ----
#pragma unroll
        for (int ks = 0; ks < 2; ++ks) {
            bf16x8 av[4], bv[4];
#pragma unroll
            for (int mi = 0; mi < 4; ++mi) {
                const int r = wm * 64 + mi * 16 + (ln & 15);
                const int c = ks * 4 + (ln >> 4);
                const int slot = c ^ (r & 7);
                av[mi] = *(const bf16x8*)&sA[r * 64 + slot * 8];
            }
#pragma unroll
            for (int ni = 0; ni < 4; ++ni) {
                const int r = wn * 64 + ni * 16 + (ln & 15);
                const int c = ks * 4 + (ln >> 4);
                const int slot = c ^ (r & 7);
                bv[ni] = *(const bf16x8*)&sB[r * 64 + slot * 8];
            }
#pragma unroll
            for (int mi = 0; mi < 4; ++mi)
#pragma unroll
                for (int ni = 0; ni < 4; ++ni)
                    acc[mi][ni] = __builtin_amdgcn_mfma_f32_16x16x32_bf16(
                        av[mi], bv[ni], acc[mi][ni], 0, 0, 0);
        }
        __syncthreads();
    }

    // ---- epilogue: bias (+ReLU) ----
    const float* bs = bias + (size_t)day * NT + n0;
#pragma unroll
    for (int ni = 0; ni < 4; ++ni) {
        const int col = wn * 64 + ni * 16 + (ln & 15);
        const float bval = bs[col];
#pragma unroll
        for (int mi = 0; mi < 4; ++mi) {
#pragma unroll
            for (int i = 0; i < 4; ++i) {
                const int row = wm * 64 + mi * 16 + (ln >> 4) * 4 + i;
                float v = acc[mi][ni][i] + bval;
                if (RELU) v = fmaxf(v, 0.f);
                const size_t off = (size_t)bz * MT * NT + (size_t)(m0 + row) * NT + n0 + col;
                if (OUT_BF16) ((u16*)Call)[off] = f2bf(v);
                else          ((float*)Call)[off] = v;
            }
        }
    }
}

// In-place LayerNorm over last dim (512) + gamma/beta. 1 wave per row.
__global__ __launch_bounds__(256)
void ln_kernel(float* __restrict__ y, const int* __restrict__ didx,
               const float* __restrict__ gamma, const float* __restrict__ beta)
{
    const int row = blockIdx.x * 4 + (threadIdx.x >> 6);
    const int ln  = threadIdx.x & 63;
    const int b   = row >> 9;                  // T = 512 rows per sample
    const int day = didx[b];
    float* p = y + (size_t)row * DOUT;

    float4 v0 = ((const float4*)p)[ln];        // elems [4ln, 4ln+4)
    float4 v1 = ((const float4*)p)[64 + ln];   // elems [256+4ln, ...)
    float s = v0.x + v0.y + v0.z + v0.w + v1.x + v1.y + v1.z + v1.w;
    float q = v0.x * v0.x + v0.y * v0.y + v0.z * v0.z + v0.w * v0.w
            + v1.x * v1.x + v1.y * v1.y + v1.z * v1.z + v1.w * v1.w;
#pragma unroll
    for (int o = 32; o; o >>= 1) { s += __shfl_xor(s, o); q += __shfl_xor(q, o); }
    const float mean = s * (1.f / 512.f);
    const float var  = q * (1.f / 512.f) - mean * mean;
    const float rstd = rsqrtf(var + 1e-5f);

    const float4* g  = (const float4*)(gamma + (size_t)day * DOUT);
    const float4* bt = (const float4*)(beta  + (size_t)day * DOUT);
    float4 g0 = g[ln], g1 = g[64 + ln], bb0 = bt[ln], bb1 = bt[64 + ln];
    float4 o0, o1;
    o0.x = (v0.x - mean) * rstd * g0.x + bb0.x;
    o0.y = (v0.y - mean) * rstd * g0.y + bb0.y;
    o0.z = (v0.z - mean) * rstd * g0.z + bb0.z;
    o0.w = (v0.w - mean) * rstd * g0.w + bb0.w;
    o1.x = (v1.x - mean) * rstd * g1.x + bb1.x;
    o1.y = (v1.y - mean) * rstd * g1.y + bb1.y;
    o1.z = (v1.z - mean) * rstd * g1.z + bb1.z;
    o1.w = (v1.w - mean) * rstd * g1.w + bb1.w;
    ((float4*)p)[ln] = o0;
    ((float4*)p)[64 + ln] = o1;
}

extern "C" void kernel_launch(void* const* d_in, const int* in_sizes, int n_in,
                              void* d_out, int out_size, void* d_ws, size_t ws_size,
                              hipStream_t stream)
{
    const float* x     = (const float*)d_in[0];
    const int*   didx  = (const int*)d_in[1];
    const float* W1    = (const float*)d_in[2];
    const float* b1    = (const float*)d_in[3];
    const float* W2    = (const float*)d_in[4];
    const float* b2    = (const float*)d_in[5];
    const float* gamma = (const float*)d_in[6];
    const float* beta  = (const float*)d_in[7];
    float* out = (float*)d_out;

    char* ws = (char*)d_ws;
    u16* W1T = (u16*)ws;                        // [24][1024][512] bf16 = 25.2 MB
    u16* W2T = (u16*)(ws + 25165824);           // [24][512][1024] bf16 = 25.2 MB
    u16* h   = (u16*)(ws + 50331648);           // [64][512][1024] bf16 = 67.1 MB

    transpose_w<<<dim3(DHID / 32, DIN / 32, NDAYS), dim3(32, 8), 0, stream>>>(W1, W1T, DIN, DHID);
    transpose_w<<<dim3(DOUT / 32, DHID / 32, NDAYS), dim3(32, 8), 0, stream>>>(W2, W2T, DHID, DOUT);

    gemm_day<T_, DHID, DIN, true, true, true>
        <<<dim3(T_ / 128, DHID / 128, B_), 256, 0, stream>>>(x, W1T, b1, didx, h);

    gemm_day<T_, DOUT, DHID, false, false, false>
        <<<dim3(T_ / 128, DOUT / 128, B_), 256, 0, stream>>>(h, W2T, b2, didx, out);

    ln_kernel<<<(B_ * T_) / 4, 256, 0, stream>>>(out, didx, gamma, beta);
}

// Round 2
// 166.575 us; speedup vs baseline: 1.1690x; 1.1690x over previous
//
#include <hip/hip_runtime.h>

#define B_    64
#define T_    512
#define DIN   512
#define DHID  1024
#define DOUT  512
#define NDAYS 24

typedef unsigned short u16;
typedef __bf16 bf16x8 __attribute__((ext_vector_type(8)));
typedef u16    u16x8  __attribute__((ext_vector_type(8)));
typedef float  f32x4  __attribute__((ext_vector_type(4)));

static __device__ __forceinline__ u16 f2bf(float f) {
    union { float f; unsigned u; } v; v.f = f;
    unsigned r = v.u + 0x7FFFu + ((v.u >> 16) & 1u);
    return (u16)(r >> 16);
}

static __device__ __forceinline__ void gload_lds16(const void* g, void* l) {
    __builtin_amdgcn_global_load_lds(
        (const __attribute__((address_space(1))) void*)g,
        (__attribute__((address_space(3))) void*)l, 16, 0, 0);
}

// W[d][R][C] fp32  ->  WT[d][C][R] bf16
__global__ __launch_bounds__(256)
void transpose_w(const float* __restrict__ W, u16* __restrict__ WT, int R, int C) {
    __shared__ float t[32][33];
    const int d  = blockIdx.z;
    const int r0 = blockIdx.y * 32, c0 = blockIdx.x * 32;
    const int tx = threadIdx.x, ty = threadIdx.y;   // 32 x 8
    const float* Wd = W + (size_t)d * R * C;
    u16* WTd = WT + (size_t)d * R * C;
#pragma unroll
    for (int i = 0; i < 4; ++i)
        t[ty + i * 8][tx] = Wd[(size_t)(r0 + ty + i * 8) * C + c0 + tx];
    __syncthreads();
#pragma unroll
    for (int i = 0; i < 4; ++i)
        WTd[(size_t)(c0 + ty + i * 8) * R + r0 + tx] = f2bf(t[tx][ty + i * 8]);
}

// fp32 -> bf16, 8 elems/thread, grid-stride
__global__ __launch_bounds__(256)
void cvt_bf16(const float* __restrict__ in, u16* __restrict__ outp, int n8) {
    int i = blockIdx.x * 256 + threadIdx.x;
    const int stride = gridDim.x * 256;
    for (; i < n8; i += stride) {
        float4 a = ((const float4*)in)[i * 2];
        float4 b = ((const float4*)in)[i * 2 + 1];
        u16x8 p;
        p[0] = f2bf(a.x); p[1] = f2bf(a.y); p[2] = f2bf(a.z); p[3] = f2bf(a.w);
        p[4] = f2bf(b.x); p[5] = f2bf(b.y); p[6] = f2bf(b.z); p[7] = f2bf(b.w);
        ((u16x8*)outp)[i] = p;
    }
}

// ---------------- 256x256-tile 8-phase GEMM (T1+T2+T3+T4+T5) ----------------
// C[bz] = act(A[bz] @ BT[day]^T + bias[day]).
// 8 waves: wm=wv>>2 (2), wn=wv&3 (4). Per-wave out: rows {mq*128+wm*64+..},
// cols {nq*128+wn*32+..} -> quadrant (mq,nq) per phase; each phase touches
// exactly A-half(mq) and B-half(nq), so halves free progressively.
// Stage schedule: p0:(t+1).A1  p1:(t+1).B1  p2:(t+2).A0  p3:(t+2).B0.
// Boundary wait (before p3's barrier): vmcnt(4) => tile t+1 fully landed.
// LDS 16B-chunk XOR swizzle (slot = chunk ^ (row&7)); verified conflict-free
// (round-1 SQ_LDS_BANK_CONFLICT == 0) and gload_lds-compatible (linear dest,
// pre-swizzled source).
template<int MT, int NT, int KT, bool RELU, bool OUT_BF16>
__global__ __launch_bounds__(512, 1)
void gemm8(const u16* __restrict__ Aall,
           const u16* __restrict__ BT,      // [NDAYS][NT][KT]
           const float* __restrict__ bias,  // [NDAYS][NT]
           const int* __restrict__ didx,
           void* __restrict__ Call)
{
    constexpr int GX = MT / 256;
    constexpr int GY = NT / 256;
    constexpr int NWG = GX * GY * B_;
    constexpr int NT_K = KT / 64;
    static_assert(NT_K >= 2 && (NWG % 8) == 0, "geometry");

    // T1: bijective XCD swizzle; XCD k gets 8 consecutive samples (A reuse in L2)
    constexpr int Q = NWG / 8;
    const int hw = blockIdx.x;
    const int l  = (hw & 7) * Q + (hw >> 3);
    const int bx = l % GX;
    const int by = (l / GX) % GY;
    const int bz = l / (GX * GY);

    const int day = didx[bz];
    const int m0 = bx * 256, n0 = by * 256;
    const int tid = threadIdx.x;
    const int wv = tid >> 6, ln = tid & 63;
    const int wm = wv >> 2, wn = wv & 3;

    __shared__ __align__(16) u16 sA[2][256 * 64];
    __shared__ __align__(16) u16 sB[2][256 * 64];

    const u16* Ab = Aall + (size_t)bz * MT * KT + (size_t)m0 * KT;
    const u16* Bt = BT + (size_t)day * NT * KT + (size_t)n0 * KT;

    auto stageA = [&](int buf, int t, int h) {
#pragma unroll
        for (int c = 0; c < 2; ++c) {
            const int rl = h * 128 + wv * 16 + c * 8 + (ln >> 3);
            const int cd = (ln & 7) ^ (rl & 7);
            gload_lds16(Ab + (size_t)rl * KT + t * 64 + cd * 8,
                        (char*)&sA[buf][(h * 128 + wv * 16 + c * 8) * 64]);
        }
    };
    auto stageB = [&](int buf, int t, int h) {
#pragma unroll
        for (int c = 0; c < 2; ++c) {
            const int rl = h * 128 + wv * 16 + c * 8 + (ln >> 3);
            const int cd = (ln & 7) ^ (rl & 7);
            gload_lds16(Bt + (size_t)rl * KT + t * 64 + cd * 8,
                        (char*)&sB[buf][(h * 128 + wv * 16 + c * 8) * 64]);
        }
    };

    f32x4 acc[8][4];
#pragma unroll
    for (int i = 0; i < 8; ++i)
#pragma unroll
        for (int j = 0; j < 4; ++j)
            acc[i][j] = (f32x4){0.f, 0.f, 0.f, 0.f};

    // prologue: tile0 all 4 halves + tile1 A0,B0; then t0 guaranteed landed
    stageA(0, 0, 0); stageB(0, 0, 0); stageA(0, 0, 1); stageB(0, 0, 1);
    stageA(1, 1, 0); stageB(1, 1, 0);
    asm volatile("s_waitcnt vmcnt(4)" ::: "memory");
    __builtin_amdgcn_s_barrier();

    for (int t = 0; t < NT_K; ++t) {
        const int buf = t & 1;
        const u16* sAb = sA[buf];
        const u16* sBb = sB[buf];
        bf16x8 av[2][4], bv[2][2];

#pragma unroll
        for (int p = 0; p < 4; ++p) {
            const int mq = p >> 1, nq = p & 1;
            if (p == 0 || p == 2) {
#pragma unroll
                for (int ks = 0; ks < 2; ++ks)
#pragma unroll
                    for (int mi = 0; mi < 4; ++mi) {
                        const int r = mq * 128 + wm * 64 + mi * 16 + (ln & 15);
                        const int slot = (ks * 4 + (ln >> 4)) ^ (r & 7);
                        av[ks][mi] = *(const bf16x8*)&sAb[r * 64 + slot * 8];
                    }
            }
#pragma unroll
            for (int ks = 0; ks < 2; ++ks)
#pragma unroll
                for (int ni = 0; ni < 2; ++ni) {
                    const int r = nq * 128 + wn * 32 + ni * 16 + (ln & 15);
                    const int slot = (ks * 4 + (ln >> 4)) ^ (r & 7);
                    bv[ks][ni] = *(const bf16x8*)&sBb[r * 64 + slot * 8];
                }
            // stage one half (guarded)
            if (p == 0)      { if (t + 1 < NT_K) stageA(buf ^ 1, t + 1, 1); }
            else if (p == 1) { if (t + 1 < NT_K) stageB(buf ^ 1, t + 1, 1); }
            else if (p == 2) { if (t + 2 < NT_K) stageA(buf, t + 2, 0); }
            else             { if (t + 2 < NT_K) stageB(buf, t + 2, 0); }

            __builtin_amdgcn_s_barrier();
            asm volatile("s_waitcnt lgkmcnt(0)" ::: "memory");
            __builtin_amdgcn_sched_barrier(0);
            __builtin_amdgcn_s_setprio(1);
#pragma unroll
            for (int ks = 0; ks < 2; ++ks)
#pragma unroll
                for (int mi = 0; mi < 4; ++mi)
#pragma unroll
                    for (int ni = 0; ni < 2; ++ni)
                        acc[mq * 4 + mi][nq * 2 + ni] =
                            __builtin_amdgcn_mfma_f32_16x16x32_bf16(
                                av[ks][mi], bv[ks][ni],
                                acc[mq * 4 + mi][nq * 2 + ni], 0, 0, 0);
            __builtin_amdgcn_s_setprio(0);
            if (p == 3) {
                if (t + 2 < NT_K) asm volatile("s_waitcnt vmcnt(4)" ::: "memory");
                else              asm volatile("s_waitcnt vmcnt(0)" ::: "memory");
            }
            __builtin_amdgcn_s_barrier();
        }
    }

    // epilogue: bias (+ReLU), scattered 4-row columns per lane
    const float* bs = bias + (size_t)day * NT + n0;
#pragma unroll
    for (int nq = 0; nq < 2; ++nq)
#pragma unroll
        for (int ni = 0; ni < 2; ++ni) {
            const int col = nq * 128 + wn * 32 + ni * 16 + (ln & 15);
            const float bval = bs[col];
#pragma unroll
            for (int mq = 0; mq < 2; ++mq)
#pragma unroll
                for (int mi = 0; mi < 4; ++mi)
#pragma unroll
                    for (int i = 0; i < 4; ++i) {
                        const int row = mq * 128 + wm * 64 + mi * 16 + (ln >> 4) * 4 + i;
                        float v = acc[mq * 4 + mi][nq * 2 + ni][i] + bval;
                        if (RELU) v = fmaxf(v, 0.f);
                        const size_t off = (size_t)bz * MT * NT + (size_t)(m0 + row) * NT + (n0 + col);
                        if (OUT_BF16) ((u16*)Call)[off] = f2bf(v);
                        else          ((float*)Call)[off] = v;
                    }
        }
}

// In-place LayerNorm over last dim (512) + gamma/beta. 1 wave per row.
__global__ __launch_bounds__(256)
void ln_kernel(float* __restrict__ y, const int* __restrict__ didx,
               const float* __restrict__ gamma, const float* __restrict__ beta)
{
    const int row = blockIdx.x * 4 + (threadIdx.x >> 6);
    const int ln  = threadIdx.x & 63;
    const int b   = row >> 9;
    const int day = didx[b];
    float* p = y + (size_t)row * DOUT;

    float4 v0 = ((const float4*)p)[ln];
    float4 v1 = ((const float4*)p)[64 + ln];
    float s = v0.x + v0.y + v0.z + v0.w + v1.x + v1.y + v1.z + v1.w;
    float q = v0.x * v0.x + v0.y * v0.y + v0.z * v0.z + v0.w * v0.w
            + v1.x * v1.x + v1.y * v1.y + v1.z * v1.z + v1.w * v1.w;
#pragma unroll
    for (int o = 32; o; o >>= 1) { s += __shfl_xor(s, o); q += __shfl_xor(q, o); }
    const float mean = s * (1.f / 512.f);
    const float var  = q * (1.f / 512.f) - mean * mean;
    const float rstd = rsqrtf(var + 1e-5f);

    const float4* g  = (const float4*)(gamma + (size_t)day * DOUT);
    const float4* bt = (const float4*)(beta  + (size_t)day * DOUT);
    float4 g0 = g[ln], g1 = g[64 + ln], bb0 = bt[ln], bb1 = bt[64 + ln];
    float4 o0, o1;
    o0.x = (v0.x - mean) * rstd * g0.x + bb0.x;
    o0.y = (v0.y - mean) * rstd * g0.y + bb0.y;
    o0.z = (v0.z - mean) * rstd * g0.z + bb0.z;
    o0.w = (v0.w - mean) * rstd * g0.w + bb0.w;
    o1.x = (v1.x - mean) * rstd * g1.x + bb1.x;
    o1.y = (v1.y - mean) * rstd * g1.y + bb1.y;
    o1.z = (v1.z - mean) * rstd * g1.z + bb1.z;
    o1.w = (v1.w - mean) * rstd * g1.w + bb1.w;
    ((float4*)p)[ln] = o0;
    ((float4*)p)[64 + ln] = o1;
}

extern "C" void kernel_launch(void* const* d_in, const int* in_sizes, int n_in,
                              void* d_out, int out_size, void* d_ws, size_t ws_size,
                              hipStream_t stream)
{
    const float* x     = (const float*)d_in[0];
    const int*   didx  = (const int*)d_in[1];
    const float* W1    = (const float*)d_in[2];
    const float* b1    = (const float*)d_in[3];
    const float* W2    = (const float*)d_in[4];
    const float* b2    = (const float*)d_in[5];
    const float* gamma = (const float*)d_in[6];
    const float* beta  = (const float*)d_in[7];
    float* out = (float*)d_out;

    char* ws = (char*)d_ws;
    u16* W1T = (u16*)ws;                       // [24][1024][512] bf16 = 25.2 MB
    u16* h   = (u16*)(ws + 25165824);          // [64][512][1024] bf16 = 67.1 MB
    u16* xb  = (u16*)(ws + 92274688);          // [64][512][512]  bf16 = 33.6 MB
    u16* W2T = xb;                             // overlays xb AFTER gemm1 (stream-serial)

    transpose_w<<<dim3(DHID / 32, DIN / 32, NDAYS), dim3(32, 8), 0, stream>>>(W1, W1T, DIN, DHID);
    cvt_bf16<<<2048, 256, 0, stream>>>(x, xb, B_ * T_ * DIN / 8);

    gemm8<T_, DHID, DIN, true, true>
        <<<dim3(2 * 4 * B_), 512, 0, stream>>>(xb, W1T, b1, didx, h);

    transpose_w<<<dim3(DOUT / 32, DHID / 32, NDAYS), dim3(32, 8), 0, stream>>>(W2, W2T, DHID, DOUT);

    gemm8<T_, DOUT, DHID, false, false>
        <<<dim3(2 * 2 * B_), 512, 0, stream>>>(h, W2T, b2, didx, out);

    ln_kernel<<<(B_ * T_) / 4, 256, 0, stream>>>(out, didx, gamma, beta);
}